// Round 2
// baseline (466.252 us; speedup 1.0000x reference)
//
#include <hip/hip_runtime.h>
#include <hip/hip_bf16.h>

typedef __bf16 bf16_t;
typedef __bf16 bf16x8 __attribute__((ext_vector_type(8)));
typedef float f32x4 __attribute__((ext_vector_type(4)));

#define NN 8192
#define EE 262144
#define NF 1024
#define NH 512
#define ZD 32

// ---------------- f32 -> bf16 bulk convert (8 elems/thread) ----------------
__global__ __launch_bounds__(256) void k_cvt(const float* __restrict__ in,
                                             bf16_t* __restrict__ out, int n8) {
  int i = blockIdx.x * 256 + threadIdx.x;
  if (i >= n8) return;
  const float4 a = ((const float4*)in)[i * 2];
  const float4 b = ((const float4*)in)[i * 2 + 1];
  bf16x8 o;
  o[0] = (bf16_t)a.x; o[1] = (bf16_t)a.y; o[2] = (bf16_t)a.z; o[3] = (bf16_t)a.w;
  o[4] = (bf16_t)b.x; o[5] = (bf16_t)b.y; o[6] = (bf16_t)b.z; o[7] = (bf16_t)b.w;
  ((bf16x8*)out)[i] = o;
}

// ---------------- transpose + convert: f32 [R,C] -> bf16 [C,R] ----------------
__global__ __launch_bounds__(256) void k_transpose_cvt(const float* __restrict__ in,
                                                       bf16_t* __restrict__ out,
                                                       int R, int C) {
  __shared__ float tile[32][33];
  const int c0 = blockIdx.x * 32, r0 = blockIdx.y * 32;
  const int tx = threadIdx.x & 31, ty = threadIdx.x >> 5;
  #pragma unroll
  for (int i = ty; i < 32; i += 8)
    tile[i][tx] = in[(size_t)(r0 + i) * C + (c0 + tx)];
  __syncthreads();
  #pragma unroll
  for (int i = ty; i < 32; i += 8)
    out[(size_t)(c0 + i) * R + (r0 + tx)] = (bf16_t)tile[tx][i];
}

// ---------------- CSR row_ptr from sorted rows ----------------
__global__ void k_rowptr(const int* __restrict__ rows, int* __restrict__ rp,
                         int n, int e) {
  int r = blockIdx.x * 256 + threadIdx.x;
  if (r > n) return;
  if (r == n) { rp[n] = e; return; }
  int lo = 0, hi = e;
  while (lo < hi) { int mid = (lo + hi) >> 1; if (rows[mid] < r) lo = mid + 1; else hi = mid; }
  rp[r] = lo;
}

// ---------------- GEMM: C[M,N] f32 = A[M,K] bf16 @ Bt[N,K]^T, 128x128 tile ----------------
__global__ __launch_bounds__(256) void k_gemm_bt_128x128(
    const bf16_t* __restrict__ A, const bf16_t* __restrict__ Bt,
    float* __restrict__ C, int M, int N, int K) {
  __shared__ bf16_t As[128 * 32];
  __shared__ bf16_t Bs[128 * 32];
  const int tid = threadIdx.x;
  const int lane = tid & 63, wave = tid >> 6;
  const int wx = wave & 1, wy = wave >> 1;
  const int m0 = blockIdx.y * 128, n0 = blockIdx.x * 128;
  const int q = lane >> 4, ml = lane & 15;

  const int sr = tid >> 2, ss = tid & 3;
  const int sw_lo = sr * 32 + ((ss ^ (sr & 3)) * 8);
  const int sw_hi = sw_lo + 64 * 32;

  int a_off[4], b_off[4];
  #pragma unroll
  for (int i = 0; i < 4; ++i) {
    int m = wy * 64 + i * 16 + ml;
    a_off[i] = m * 32 + ((q ^ (m & 3)) * 8);
    int n = wx * 64 + i * 16 + ml;
    b_off[i] = n * 32 + ((q ^ (n & 3)) * 8);
  }

  f32x4 acc[4][4];
  #pragma unroll
  for (int i = 0; i < 4; ++i)
    #pragma unroll
    for (int j = 0; j < 4; ++j)
      acc[i][j] = (f32x4){0.f, 0.f, 0.f, 0.f};

  const bf16_t* ga = A + (size_t)(m0 + sr) * K + ss * 8;
  const bf16_t* gb = Bt + (size_t)(n0 + sr) * K + ss * 8;
  const size_t stride64 = (size_t)64 * K;

  for (int k0 = 0; k0 < K; k0 += 32) {
    int4 va0 = *(const int4*)(ga + k0);
    int4 va1 = *(const int4*)(ga + stride64 + k0);
    int4 vb0 = *(const int4*)(gb + k0);
    int4 vb1 = *(const int4*)(gb + stride64 + k0);
    __syncthreads();
    *(int4*)(&As[sw_lo]) = va0;
    *(int4*)(&As[sw_hi]) = va1;
    *(int4*)(&Bs[sw_lo]) = vb0;
    *(int4*)(&Bs[sw_hi]) = vb1;
    __syncthreads();
    bf16x8 af[4], bfr[4];
    #pragma unroll
    for (int i = 0; i < 4; ++i) af[i] = *(const bf16x8*)(&As[a_off[i]]);
    #pragma unroll
    for (int j = 0; j < 4; ++j) bfr[j] = *(const bf16x8*)(&Bs[b_off[j]]);
    #pragma unroll
    for (int i = 0; i < 4; ++i)
      #pragma unroll
      for (int j = 0; j < 4; ++j)
        acc[i][j] = __builtin_amdgcn_mfma_f32_16x16x32_bf16(af[i], bfr[j], acc[i][j], 0, 0, 0);
  }

  #pragma unroll
  for (int i = 0; i < 4; ++i) {
    const int row = m0 + wy * 64 + i * 16 + q * 4;
    #pragma unroll
    for (int j = 0; j < 4; ++j) {
      const int col = n0 + wx * 64 + j * 16 + ml;
      #pragma unroll
      for (int r = 0; r < 4; ++r)
        C[(size_t)(row + r) * N + col] = acc[i][j][r];
    }
  }
}

// ---------------- GEMM: 128x64 tile (N=64), C f32 ----------------
__global__ __launch_bounds__(256) void k_gemm_bt_128x64(
    const bf16_t* __restrict__ A, const bf16_t* __restrict__ Bt,
    float* __restrict__ C, int M, int N, int K) {
  __shared__ bf16_t As[128 * 32];
  __shared__ bf16_t Bs[64 * 32];
  const int tid = threadIdx.x;
  const int lane = tid & 63, wave = tid >> 6;
  const int m0 = blockIdx.y * 128;
  const int q = lane >> 4, ml = lane & 15;
  const int sr = tid >> 2, ss = tid & 3;
  const int sw_lo = sr * 32 + ((ss ^ (sr & 3)) * 8);
  const int sw_hi = sw_lo + 64 * 32;

  int a_off[2], b_off[4];
  #pragma unroll
  for (int i = 0; i < 2; ++i) {
    int m = wave * 32 + i * 16 + ml;
    a_off[i] = m * 32 + ((q ^ (m & 3)) * 8);
  }
  #pragma unroll
  for (int j = 0; j < 4; ++j) {
    int n = j * 16 + ml;
    b_off[j] = n * 32 + ((q ^ (n & 3)) * 8);
  }

  f32x4 acc[2][4];
  #pragma unroll
  for (int i = 0; i < 2; ++i)
    #pragma unroll
    for (int j = 0; j < 4; ++j)
      acc[i][j] = (f32x4){0.f, 0.f, 0.f, 0.f};

  const bf16_t* ga = A + (size_t)(m0 + sr) * K + ss * 8;
  const bf16_t* gb = Bt + (size_t)sr * K + ss * 8;
  const size_t stride64 = (size_t)64 * K;

  for (int k0 = 0; k0 < K; k0 += 32) {
    int4 va0 = *(const int4*)(ga + k0);
    int4 va1 = *(const int4*)(ga + stride64 + k0);
    int4 vb0 = *(const int4*)(gb + k0);
    __syncthreads();
    *(int4*)(&As[sw_lo]) = va0;
    *(int4*)(&As[sw_hi]) = va1;
    *(int4*)(&Bs[sw_lo]) = vb0;
    __syncthreads();
    bf16x8 af[2], bfr[4];
    #pragma unroll
    for (int i = 0; i < 2; ++i) af[i] = *(const bf16x8*)(&As[a_off[i]]);
    #pragma unroll
    for (int j = 0; j < 4; ++j) bfr[j] = *(const bf16x8*)(&Bs[b_off[j]]);
    #pragma unroll
    for (int i = 0; i < 2; ++i)
      #pragma unroll
      for (int j = 0; j < 4; ++j)
        acc[i][j] = __builtin_amdgcn_mfma_f32_16x16x32_bf16(af[i], bfr[j], acc[i][j], 0, 0, 0);
  }

  #pragma unroll
  for (int i = 0; i < 2; ++i) {
    const int row = m0 + wave * 32 + i * 16 + q * 4;
    #pragma unroll
    for (int j = 0; j < 4; ++j) {
      const int col = j * 16 + ml;
      #pragma unroll
      for (int r = 0; r < 4; ++r)
        C[(size_t)(row + r) * N + col] = acc[i][j][r];
    }
  }
}

// ---------------- SpMM D=512: h = relu(spmm(XW0) + b0), bf16 out ----------------
__global__ __launch_bounds__(256) void k_spmm_h(
    const int* __restrict__ rp, const int* __restrict__ cols,
    const float* __restrict__ vals, const float* __restrict__ XW0,
    const float* __restrict__ b0, bf16_t* __restrict__ h) {
  const int r = blockIdx.x;
  const int t = threadIdx.x;
  const int beg = rp[r], end = rp[r + 1];
  float acc0 = 0.f, acc1 = 0.f;
  for (int e = beg; e < end; ++e) {
    const float v = vals[e];
    const float* src = XW0 + (size_t)cols[e] * NH;
    acc0 += v * src[t];
    acc1 += v * src[t + 256];
  }
  acc0 += b0[t];
  acc1 += b0[t + 256];
  h[(size_t)r * NH + t]       = (bf16_t)fmaxf(acc0, 0.f);
  h[(size_t)r * NH + t + 256] = (bf16_t)fmaxf(acc1, 0.f);
}

// ---------------- SpMM D=64: z/mu/logvar (f32 out) + bf16 z copy ----------------
__global__ __launch_bounds__(64) void k_spmm_z(
    const int* __restrict__ rp, const int* __restrict__ cols,
    const float* __restrict__ vals, const float* __restrict__ HW,
    const float* __restrict__ b1, const float* __restrict__ b2,
    float* __restrict__ out_z, float* __restrict__ out_mu,
    float* __restrict__ out_lv, bf16_t* __restrict__ zb) {
  const int r = blockIdx.x;
  const int t = threadIdx.x;  // 64
  const int beg = rp[r], end = rp[r + 1];
  float acc = 0.f;
  for (int e = beg; e < end; ++e)
    acc += vals[e] * HW[(size_t)cols[e] * 64 + t];
  const float b = (t < ZD) ? b1[t] : b2[t - ZD];
  const float v = fmaxf(acc + b, 0.f);
  if (t < ZD) {
    out_mu[(size_t)r * ZD + t] = v;
    out_z[(size_t)r * ZD + t] = v;
    zb[(size_t)r * ZD + t] = (bf16_t)v;
  } else {
    out_lv[(size_t)r * ZD + (t - ZD)] = v;
  }
}

// ---------------- decoder: out = sigmoid(Z @ Z^T) f32, K=32 -> single MFMA/tile ----------------
__global__ __launch_bounds__(256) void k_decoder(const bf16_t* __restrict__ Z,
                                                 float* __restrict__ out) {
  __shared__ bf16_t Zr[128 * 32];
  __shared__ bf16_t Zc[128 * 32];
  const int tid = threadIdx.x;
  const int lane = tid & 63, wave = tid >> 6;
  const int wx = wave & 1, wy = wave >> 1;
  const int m0 = blockIdx.y * 128, n0 = blockIdx.x * 128;
  const int q = lane >> 4, ml = lane & 15;
  const int sr = tid >> 2, ss = tid & 3;
  const int sw_lo = sr * 32 + ((ss ^ (sr & 3)) * 8);
  const int sw_hi = sw_lo + 64 * 32;

  *(int4*)(&Zr[sw_lo]) = *((const int4*)(Z + (size_t)(m0 + sr) * ZD) + ss);
  *(int4*)(&Zr[sw_hi]) = *((const int4*)(Z + (size_t)(m0 + sr + 64) * ZD) + ss);
  *(int4*)(&Zc[sw_lo]) = *((const int4*)(Z + (size_t)(n0 + sr) * ZD) + ss);
  *(int4*)(&Zc[sw_hi]) = *((const int4*)(Z + (size_t)(n0 + sr + 64) * ZD) + ss);
  __syncthreads();

  bf16x8 af[4], bfr[4];
  #pragma unroll
  for (int i = 0; i < 4; ++i) {
    int m = wy * 64 + i * 16 + ml;
    af[i] = *(const bf16x8*)(&Zr[m * 32 + ((q ^ (m & 3)) * 8)]);
    int n = wx * 64 + i * 16 + ml;
    bfr[i] = *(const bf16x8*)(&Zc[n * 32 + ((q ^ (n & 3)) * 8)]);
  }
  const f32x4 zero = (f32x4){0.f, 0.f, 0.f, 0.f};
  #pragma unroll
  for (int i = 0; i < 4; ++i) {
    const int row = m0 + wy * 64 + i * 16 + q * 4;
    #pragma unroll
    for (int j = 0; j < 4; ++j) {
      const int col = n0 + wx * 64 + j * 16 + ml;
      f32x4 c = __builtin_amdgcn_mfma_f32_16x16x32_bf16(af[i], bfr[j], zero, 0, 0, 0);
      #pragma unroll
      for (int r = 0; r < 4; ++r)
        out[(size_t)(row + r) * NN + col] = 1.f / (1.f + __expf(-c[r]));
    }
  }
}

extern "C" void kernel_launch(void* const* d_in, const int* in_sizes, int n_in,
                              void* d_out, int out_size, void* d_ws, size_t ws_size,
                              hipStream_t stream) {
  const float* x        = (const float*)d_in[0];
  const float* adj_vals = (const float*)d_in[1];
  const float* W0       = (const float*)d_in[2];
  const float* b0       = (const float*)d_in[3];
  const float* W1       = (const float*)d_in[4];
  const float* b1       = (const float*)d_in[5];
  const float* W2       = (const float*)d_in[6];
  const float* b2       = (const float*)d_in[7];
  const int* adj_rows   = (const int*)d_in[8];
  const int* adj_cols   = (const int*)d_in[9];

  char* ws = (char*)d_ws;
  float*  XW0 = (float*)(ws);                    // 8192*512*4   = 16777216
  float*  HW  = (float*)(ws + 16777216);         // 8192*64*4    =  2097152
  bf16_t* h   = (bf16_t*)(ws + 18874368);        // 8192*512*2   =  8388608
  bf16_t* W0t = (bf16_t*)(ws + 27262976);        // 512*1024*2   =  1048576
  bf16_t* Wct = (bf16_t*)(ws + 28311552);        // 64*512*2     =    65536
  bf16_t* xb  = (bf16_t*)(ws + 28377088);        // 8192*1024*2  = 16777216
  bf16_t* zb  = (bf16_t*)(ws + 45154304);        // 8192*32*2    =   524288
  int*    rp  = (int*)(ws + 45678592);           // 8193*4

  float* out     = (float*)d_out;
  float* out_adj = out;
  float* out_z   = out + (size_t)NN * NN;
  float* out_mu  = out_z + (size_t)NN * ZD;
  float* out_lv  = out_mu + (size_t)NN * ZD;

  // prep: convert x to bf16; transpose+convert weights; build CSR row_ptr
  k_cvt<<<(NN * NF / 8 + 255) / 256, 256, 0, stream>>>(x, xb, NN * NF / 8);
  k_transpose_cvt<<<dim3(NH / 32, NF / 32), 256, 0, stream>>>(W0, W0t, NF, NH);
  k_transpose_cvt<<<dim3(ZD / 32, NH / 32), 256, 0, stream>>>(W1, Wct, NH, ZD);
  k_transpose_cvt<<<dim3(ZD / 32, NH / 32), 256, 0, stream>>>(W2, Wct + ZD * NH, NH, ZD);
  k_rowptr<<<33, 256, 0, stream>>>(adj_rows, rp, NN, EE);

  // layer 1: XW0 = x @ W0 ; h = relu(spmm(XW0) + b0)
  k_gemm_bt_128x128<<<dim3(NH / 128, NN / 128), 256, 0, stream>>>(xb, W0t, XW0, NN, NH, NF);
  k_spmm_h<<<NN, 256, 0, stream>>>(rp, adj_cols, adj_vals, XW0, b0, h);

  // layer 2: HW = h @ [W1|W2] ; mu/logvar = relu(spmm(HW) + b)
  k_gemm_bt_128x64<<<dim3(1, NN / 128), 256, 0, stream>>>(h, Wct, HW, NN, 64, NH);
  k_spmm_z<<<NN, 64, 0, stream>>>(rp, adj_cols, adj_vals, HW, b1, b2, out_z, out_mu, out_lv, zb);

  // decoder
  k_decoder<<<dim3(NN / 128, NN / 128), 256, 0, stream>>>(zb, out_adj);
}

// Round 3
// 435.492 us; speedup vs baseline: 1.0706x; 1.0706x over previous
//
#include <hip/hip_runtime.h>
#include <hip/hip_bf16.h>

typedef __bf16 bf16_t;
typedef __bf16 bf16x8 __attribute__((ext_vector_type(8)));
typedef float f32x4 __attribute__((ext_vector_type(4)));

#define NN 8192
#define EE 262144
#define NF 1024
#define NH 512
#define ZD 32

// ---------------- f32 -> bf16 bulk convert (8 elems/thread) ----------------
__global__ __launch_bounds__(256) void k_cvt(const float* __restrict__ in,
                                             bf16_t* __restrict__ out, int n8) {
  int i = blockIdx.x * 256 + threadIdx.x;
  if (i >= n8) return;
  const float4 a = ((const float4*)in)[i * 2];
  const float4 b = ((const float4*)in)[i * 2 + 1];
  bf16x8 o;
  o[0] = (bf16_t)a.x; o[1] = (bf16_t)a.y; o[2] = (bf16_t)a.z; o[3] = (bf16_t)a.w;
  o[4] = (bf16_t)b.x; o[5] = (bf16_t)b.y; o[6] = (bf16_t)b.z; o[7] = (bf16_t)b.w;
  ((bf16x8*)out)[i] = o;
}

// ---------------- transpose + convert: f32 [R,C] -> bf16 [C,R] ----------------
__global__ __launch_bounds__(256) void k_transpose_cvt(const float* __restrict__ in,
                                                       bf16_t* __restrict__ out,
                                                       int R, int C) {
  __shared__ float tile[32][33];
  const int c0 = blockIdx.x * 32, r0 = blockIdx.y * 32;
  const int tx = threadIdx.x & 31, ty = threadIdx.x >> 5;
  #pragma unroll
  for (int i = ty; i < 32; i += 8)
    tile[i][tx] = in[(size_t)(r0 + i) * C + (c0 + tx)];
  __syncthreads();
  #pragma unroll
  for (int i = ty; i < 32; i += 8)
    out[(size_t)(c0 + i) * R + (r0 + tx)] = (bf16_t)tile[tx][i];
}

// ---------------- W1|W2 transpose+convert in one launch: [NH,ZD]x2 -> bf16 [64,NH] ----------------
__global__ __launch_bounds__(256) void k_transpose_w12(const float* __restrict__ W1,
                                                       const float* __restrict__ W2,
                                                       bf16_t* __restrict__ out) {
  // blockIdx.y in [0, NH/32); blockIdx.z selects W1/W2
  __shared__ float tile[32][33];
  const float* in = blockIdx.z ? W2 : W1;
  bf16_t* o = out + (size_t)blockIdx.z * ZD * NH;
  const int r0 = blockIdx.y * 32;
  const int tx = threadIdx.x & 31, ty = threadIdx.x >> 5;
  #pragma unroll
  for (int i = ty; i < 32; i += 8)
    tile[i][tx] = in[(size_t)(r0 + i) * ZD + tx];  // tx < 32 == ZD
  __syncthreads();
  #pragma unroll
  for (int i = ty; i < 32; i += 8)
    o[(size_t)(i)*NH + (r0 + tx)] = (bf16_t)tile[tx][i];
}

// ---------------- CSR row_ptr from sorted rows ----------------
__global__ void k_rowptr(const int* __restrict__ rows, int* __restrict__ rp,
                         int n, int e) {
  int r = blockIdx.x * 256 + threadIdx.x;
  if (r > n) return;
  if (r == n) { rp[n] = e; return; }
  int lo = 0, hi = e;
  while (lo < hi) { int mid = (lo + hi) >> 1; if (rows[mid] < r) lo = mid + 1; else hi = mid; }
  rp[r] = lo;
}

// ---------------- GEMM1: XW0b[M,N] bf16 = A[M,K] bf16 @ Bt[N,K]^T, 128x128 tile ----------------
__global__ __launch_bounds__(256) void k_gemm_bt_128x128(
    const bf16_t* __restrict__ A, const bf16_t* __restrict__ Bt,
    bf16_t* __restrict__ C, int M, int N, int K) {
  __shared__ bf16_t As[128 * 32];
  __shared__ bf16_t Bs[128 * 32];
  const int tid = threadIdx.x;
  const int lane = tid & 63, wave = tid >> 6;
  const int wx = wave & 1, wy = wave >> 1;
  const int m0 = blockIdx.y * 128, n0 = blockIdx.x * 128;
  const int q = lane >> 4, ml = lane & 15;

  const int sr = tid >> 2, ss = tid & 3;
  const int sw_lo = sr * 32 + ((ss ^ (sr & 3)) * 8);
  const int sw_hi = sw_lo + 64 * 32;

  int a_off[4], b_off[4];
  #pragma unroll
  for (int i = 0; i < 4; ++i) {
    int m = wy * 64 + i * 16 + ml;
    a_off[i] = m * 32 + ((q ^ (m & 3)) * 8);
    int n = wx * 64 + i * 16 + ml;
    b_off[i] = n * 32 + ((q ^ (n & 3)) * 8);
  }

  f32x4 acc[4][4];
  #pragma unroll
  for (int i = 0; i < 4; ++i)
    #pragma unroll
    for (int j = 0; j < 4; ++j)
      acc[i][j] = (f32x4){0.f, 0.f, 0.f, 0.f};

  const bf16_t* ga = A + (size_t)(m0 + sr) * K + ss * 8;
  const bf16_t* gb = Bt + (size_t)(n0 + sr) * K + ss * 8;
  const size_t stride64 = (size_t)64 * K;

  for (int k0 = 0; k0 < K; k0 += 32) {
    int4 va0 = *(const int4*)(ga + k0);
    int4 va1 = *(const int4*)(ga + stride64 + k0);
    int4 vb0 = *(const int4*)(gb + k0);
    int4 vb1 = *(const int4*)(gb + stride64 + k0);
    __syncthreads();
    *(int4*)(&As[sw_lo]) = va0;
    *(int4*)(&As[sw_hi]) = va1;
    *(int4*)(&Bs[sw_lo]) = vb0;
    *(int4*)(&Bs[sw_hi]) = vb1;
    __syncthreads();
    bf16x8 af[4], bfr[4];
    #pragma unroll
    for (int i = 0; i < 4; ++i) af[i] = *(const bf16x8*)(&As[a_off[i]]);
    #pragma unroll
    for (int j = 0; j < 4; ++j) bfr[j] = *(const bf16x8*)(&Bs[b_off[j]]);
    #pragma unroll
    for (int i = 0; i < 4; ++i)
      #pragma unroll
      for (int j = 0; j < 4; ++j)
        acc[i][j] = __builtin_amdgcn_mfma_f32_16x16x32_bf16(af[i], bfr[j], acc[i][j], 0, 0, 0);
  }

  #pragma unroll
  for (int i = 0; i < 4; ++i) {
    const int row = m0 + wy * 64 + i * 16 + q * 4;
    #pragma unroll
    for (int j = 0; j < 4; ++j) {
      const int col = n0 + wx * 64 + j * 16 + ml;
      #pragma unroll
      for (int r = 0; r < 4; ++r)
        C[(size_t)(row + r) * N + col] = (bf16_t)acc[i][j][r];
    }
  }
}

// ---------------- GEMM2: HW f32 = h bf16 @ Wct^T, 128x64 tile ----------------
__global__ __launch_bounds__(256) void k_gemm_bt_128x64(
    const bf16_t* __restrict__ A, const bf16_t* __restrict__ Bt,
    float* __restrict__ C, int M, int N, int K) {
  __shared__ bf16_t As[128 * 32];
  __shared__ bf16_t Bs[64 * 32];
  const int tid = threadIdx.x;
  const int lane = tid & 63, wave = tid >> 6;
  const int m0 = blockIdx.y * 128;
  const int q = lane >> 4, ml = lane & 15;
  const int sr = tid >> 2, ss = tid & 3;
  const int sw_lo = sr * 32 + ((ss ^ (sr & 3)) * 8);
  const int sw_hi = sw_lo + 64 * 32;

  int a_off[2], b_off[4];
  #pragma unroll
  for (int i = 0; i < 2; ++i) {
    int m = wave * 32 + i * 16 + ml;
    a_off[i] = m * 32 + ((q ^ (m & 3)) * 8);
  }
  #pragma unroll
  for (int j = 0; j < 4; ++j) {
    int n = j * 16 + ml;
    b_off[j] = n * 32 + ((q ^ (n & 3)) * 8);
  }

  f32x4 acc[2][4];
  #pragma unroll
  for (int i = 0; i < 2; ++i)
    #pragma unroll
    for (int j = 0; j < 4; ++j)
      acc[i][j] = (f32x4){0.f, 0.f, 0.f, 0.f};

  const bf16_t* ga = A + (size_t)(m0 + sr) * K + ss * 8;
  const bf16_t* gb = Bt + (size_t)sr * K + ss * 8;
  const size_t stride64 = (size_t)64 * K;

  for (int k0 = 0; k0 < K; k0 += 32) {
    int4 va0 = *(const int4*)(ga + k0);
    int4 va1 = *(const int4*)(ga + stride64 + k0);
    int4 vb0 = *(const int4*)(gb + k0);
    __syncthreads();
    *(int4*)(&As[sw_lo]) = va0;
    *(int4*)(&As[sw_hi]) = va1;
    *(int4*)(&Bs[sw_lo]) = vb0;
    __syncthreads();
    bf16x8 af[2], bfr[4];
    #pragma unroll
    for (int i = 0; i < 2; ++i) af[i] = *(const bf16x8*)(&As[a_off[i]]);
    #pragma unroll
    for (int j = 0; j < 4; ++j) bfr[j] = *(const bf16x8*)(&Bs[b_off[j]]);
    #pragma unroll
    for (int i = 0; i < 2; ++i)
      #pragma unroll
      for (int j = 0; j < 4; ++j)
        acc[i][j] = __builtin_amdgcn_mfma_f32_16x16x32_bf16(af[i], bfr[j], acc[i][j], 0, 0, 0);
  }

  #pragma unroll
  for (int i = 0; i < 2; ++i) {
    const int row = m0 + wave * 32 + i * 16 + q * 4;
    #pragma unroll
    for (int j = 0; j < 4; ++j) {
      const int col = j * 16 + ml;
      #pragma unroll
      for (int r = 0; r < 4; ++r)
        C[(size_t)(row + r) * N + col] = acc[i][j][r];
    }
  }
}

// ---------------- SpMM layer1, D-chunked for L2 locality ----------------
// grid: NN*4 blocks of 64 threads. chunk = blockIdx&3 (correlates with XCD via
// round-robin dispatch -> each XCD's L2 holds one 2MB chunk of the XW0b table).
// XW0b packed as bf16x2 (uint) [NN][256]; lane t handles pair chunk*64+t.
__global__ __launch_bounds__(64) void k_spmm_h(
    const int* __restrict__ rp, const int* __restrict__ cols,
    const float* __restrict__ vals, const unsigned int* __restrict__ XW0b,
    const float* __restrict__ b0, bf16_t* __restrict__ h) {
  const int row = blockIdx.x >> 2, chunk = blockIdx.x & 3;
  const int t = threadIdx.x;
  const unsigned int* tab = XW0b + chunk * 64 + t;
  int e = rp[row];
  const int end = rp[row + 1];
  float a0 = 0.f, a1 = 0.f;
  for (; e + 1 < end; e += 2) {
    const int c0 = cols[e], c1 = cols[e + 1];
    const float v0 = vals[e], v1 = vals[e + 1];
    const unsigned int p0 = tab[(size_t)c0 * 256];
    const unsigned int p1 = tab[(size_t)c1 * 256];
    a0 += v0 * __uint_as_float(p0 << 16);
    a1 += v0 * __uint_as_float(p0 & 0xffff0000u);
    a0 += v1 * __uint_as_float(p1 << 16);
    a1 += v1 * __uint_as_float(p1 & 0xffff0000u);
  }
  if (e < end) {
    const float v0 = vals[e];
    const unsigned int p0 = tab[(size_t)cols[e] * 256];
    a0 += v0 * __uint_as_float(p0 << 16);
    a1 += v0 * __uint_as_float(p0 & 0xffff0000u);
  }
  const int d = chunk * 128 + t * 2;
  a0 += b0[d];
  a1 += b0[d + 1];
  bf16_t* o = h + (size_t)row * NH + d;
  o[0] = (bf16_t)fmaxf(a0, 0.f);
  o[1] = (bf16_t)fmaxf(a1, 0.f);
}

// ---------------- SpMM D=64: z/mu/logvar (f32 out) + bf16 z copy ----------------
__global__ __launch_bounds__(64) void k_spmm_z(
    const int* __restrict__ rp, const int* __restrict__ cols,
    const float* __restrict__ vals, const float* __restrict__ HW,
    const float* __restrict__ b1, const float* __restrict__ b2,
    float* __restrict__ out_z, float* __restrict__ out_mu,
    float* __restrict__ out_lv, bf16_t* __restrict__ zb) {
  const int r = blockIdx.x;
  const int t = threadIdx.x;  // 64
  int e = rp[r];
  const int end = rp[r + 1];
  float acc = 0.f;
  for (; e + 1 < end; e += 2) {
    const float v0 = vals[e], v1 = vals[e + 1];
    const float s0 = HW[(size_t)cols[e] * 64 + t];
    const float s1 = HW[(size_t)cols[e + 1] * 64 + t];
    acc += v0 * s0 + v1 * s1;
  }
  if (e < end) acc += vals[e] * HW[(size_t)cols[e] * 64 + t];
  const float b = (t < ZD) ? b1[t] : b2[t - ZD];
  const float v = fmaxf(acc + b, 0.f);
  if (t < ZD) {
    out_mu[(size_t)r * ZD + t] = v;
    out_z[(size_t)r * ZD + t] = v;
    zb[(size_t)r * ZD + t] = (bf16_t)v;
  } else {
    out_lv[(size_t)r * ZD + (t - ZD)] = v;
  }
}

// ---------------- decoder: out = sigmoid(Z @ Z^T) f32, K=32 -> single MFMA/tile ----------------
__global__ __launch_bounds__(256) void k_decoder(const bf16_t* __restrict__ Z,
                                                 float* __restrict__ out) {
  __shared__ bf16_t Zr[128 * 32];
  __shared__ bf16_t Zc[128 * 32];
  const int tid = threadIdx.x;
  const int lane = tid & 63, wave = tid >> 6;
  const int wx = wave & 1, wy = wave >> 1;
  const int m0 = blockIdx.y * 128, n0 = blockIdx.x * 128;
  const int q = lane >> 4, ml = lane & 15;
  const int sr = tid >> 2, ss = tid & 3;
  const int sw_lo = sr * 32 + ((ss ^ (sr & 3)) * 8);
  const int sw_hi = sw_lo + 64 * 32;

  *(int4*)(&Zr[sw_lo]) = *((const int4*)(Z + (size_t)(m0 + sr) * ZD) + ss);
  *(int4*)(&Zr[sw_hi]) = *((const int4*)(Z + (size_t)(m0 + sr + 64) * ZD) + ss);
  *(int4*)(&Zc[sw_lo]) = *((const int4*)(Z + (size_t)(n0 + sr) * ZD) + ss);
  *(int4*)(&Zc[sw_hi]) = *((const int4*)(Z + (size_t)(n0 + sr + 64) * ZD) + ss);
  __syncthreads();

  bf16x8 af[4], bfr[4];
  #pragma unroll
  for (int i = 0; i < 4; ++i) {
    int m = wy * 64 + i * 16 + ml;
    af[i] = *(const bf16x8*)(&Zr[m * 32 + ((q ^ (m & 3)) * 8)]);
    int n = wx * 64 + i * 16 + ml;
    bfr[i] = *(const bf16x8*)(&Zc[n * 32 + ((q ^ (n & 3)) * 8)]);
  }
  const f32x4 zero = (f32x4){0.f, 0.f, 0.f, 0.f};
  #pragma unroll
  for (int i = 0; i < 4; ++i) {
    const int row = m0 + wy * 64 + i * 16 + q * 4;
    #pragma unroll
    for (int j = 0; j < 4; ++j) {
      const int col = n0 + wx * 64 + j * 16 + ml;
      f32x4 c = __builtin_amdgcn_mfma_f32_16x16x32_bf16(af[i], bfr[j], zero, 0, 0, 0);
      #pragma unroll
      for (int r = 0; r < 4; ++r)
        out[(size_t)(row + r) * NN + col] = 1.f / (1.f + __expf(-c[r]));
    }
  }
}

extern "C" void kernel_launch(void* const* d_in, const int* in_sizes, int n_in,
                              void* d_out, int out_size, void* d_ws, size_t ws_size,
                              hipStream_t stream) {
  const float* x        = (const float*)d_in[0];
  const float* adj_vals = (const float*)d_in[1];
  const float* W0       = (const float*)d_in[2];
  const float* b0       = (const float*)d_in[3];
  const float* W1       = (const float*)d_in[4];
  const float* b1       = (const float*)d_in[5];
  const float* W2       = (const float*)d_in[6];
  const float* b2       = (const float*)d_in[7];
  const int* adj_rows   = (const int*)d_in[8];
  const int* adj_cols   = (const int*)d_in[9];

  char* ws = (char*)d_ws;
  bf16_t* XW0b = (bf16_t*)(ws);                  // 8192*512*2   =  8388608
  float*  HW   = (float*)(ws + 8388608);         // 8192*64*4    =  2097152
  bf16_t* h    = (bf16_t*)(ws + 10485760);       // 8192*512*2   =  8388608
  bf16_t* W0t  = (bf16_t*)(ws + 18874368);       // 512*1024*2   =  1048576
  bf16_t* Wct  = (bf16_t*)(ws + 19922944);       // 64*512*2     =    65536
  bf16_t* xb   = (bf16_t*)(ws + 19988480);       // 8192*1024*2  = 16777216
  bf16_t* zb   = (bf16_t*)(ws + 36765696);       // 8192*32*2    =   524288
  int*    rp   = (int*)(ws + 37289984);          // 8193*4

  float* out     = (float*)d_out;
  float* out_adj = out;
  float* out_z   = out + (size_t)NN * NN;
  float* out_mu  = out_z + (size_t)NN * ZD;
  float* out_lv  = out_mu + (size_t)NN * ZD;

  // prep: convert x to bf16; transpose+convert weights; build CSR row_ptr
  k_cvt<<<(NN * NF / 8 + 255) / 256, 256, 0, stream>>>(x, xb, NN * NF / 8);
  k_transpose_cvt<<<dim3(NH / 32, NF / 32), 256, 0, stream>>>(W0, W0t, NF, NH);
  k_transpose_w12<<<dim3(1, NH / 32, 2), 256, 0, stream>>>(W1, W2, Wct);
  k_rowptr<<<33, 256, 0, stream>>>(adj_rows, rp, NN, EE);

  // layer 1: XW0b = bf16(x @ W0) ; h = relu(spmm(XW0b) + b0)
  k_gemm_bt_128x128<<<dim3(NH / 128, NN / 128), 256, 0, stream>>>(xb, W0t, XW0b, NN, NH, NF);
  k_spmm_h<<<NN * 4, 64, 0, stream>>>(rp, adj_cols, adj_vals,
                                      (const unsigned int*)XW0b, b0, h);

  // layer 2: HW = h @ [W1|W2] ; mu/logvar = relu(spmm(HW) + b)
  k_gemm_bt_128x64<<<dim3(1, NN / 128), 256, 0, stream>>>(h, Wct, HW, NN, 64, NH);
  k_spmm_z<<<NN, 64, 0, stream>>>(rp, adj_cols, adj_vals, HW, b1, b2, out_z, out_mu, out_lv, zb);

  // decoder
  k_decoder<<<dim3(NN / 128, NN / 128), 256, 0, stream>>>(zb, out_adj);
}